// Round 12
// baseline (2089.692 us; speedup 1.0000x reference)
//
#include <hip/hip_runtime.h>
#include <hip/hip_bf16.h>

#define TXN 256   // Tx
#define NA 256    // n_a
#define NF 128    // features
#define NS 512    // n_s
#define TYN 10
#define VOCAB 1024

// ---- encoder LDS layout (split-bf16 planes) — IDENTICAL to verified R4/R7 ----
#define A_STR 392
#define W_STR 392
#define WL_OFF (64 * W_STR)
#define AH_OFF (2 * 64 * W_STR)
#define AL_OFF (AH_OFF + 32 * A_STR)
#define PRE_OFF_US (AL_OFF + 32 * A_STR)
#define ENC_LDS_BYTES (150528 + 32 * 68 * 4 + 64 * 4)   // 159,488 B

// ---- decoder MFMA-GEMM LDS layout (ushort indices), K-chunk = 256 ----
#define D_STR 264                        // 256 + 8 pad
#define D_WH 0
#define D_WL (64 * D_STR)                // 16896
#define D_AH (2 * 64 * D_STR)            // 33792
#define D_AL (D_AH + 32 * D_STR)         // 42240
#define D_PRE_US (D_AL + 32 * D_STR)     // 50688 -> byte 101376
#define DEC_LDS_BYTES (101376 + 32 * 68 * 4 + 64 * 4)   // 110,336 B

typedef __attribute__((ext_vector_type(8))) short bf16x8;
typedef __attribute__((ext_vector_type(8))) unsigned short u16x8;
typedef __attribute__((ext_vector_type(4))) float f32x4;

__device__ __forceinline__ float fsigmoid(float x) { return 1.f / (1.f + __expf(-x)); }
__device__ __forceinline__ float ftanh(float x)    { return 1.f - 2.f / (1.f + __expf(2.f * x)); }

__device__ __forceinline__ void split_bf16(float v, unsigned short& hi, unsigned short& lo) {
    __hip_bfloat16 h = __float2bfloat16(v);
    float rem = v - __bfloat162float(h);
    __hip_bfloat16 l = __float2bfloat16(rem);
    hi = *reinterpret_cast<unsigned short*>(&h);
    lo = *reinterpret_cast<unsigned short*>(&l);
}

__device__ __forceinline__ float agent_ld(const float* p) {
    return __hip_atomic_load(p, __ATOMIC_RELAXED, __HIP_MEMORY_SCOPE_AGENT);
}
__device__ __forceinline__ void agent_st(float* p, float v) {
    __hip_atomic_store(p, v, __ATOMIC_RELAXED, __HIP_MEMORY_SCOPE_AGENT);
}
__device__ __forceinline__ unsigned flag_ld(const unsigned* p) {
    return __hip_atomic_load(p, __ATOMIC_RELAXED, __HIP_MEMORY_SCOPE_AGENT);
}
__device__ __forceinline__ void flag_st(unsigned* p, unsigned v) {
    __hip_atomic_store(p, v, __ATOMIC_RELAXED, __HIP_MEMORY_SCOPE_AGENT);
}

// ---------------------------------------------------------------------------
// Persistent bidirectional LSTM encoder — verified R7/R11 (XCD-local groups,
// wave-specialized h staging overlapped with x-MFMAs, bf16 a_hi side-store).
// ---------------------------------------------------------------------------
__global__ __launch_bounds__(512, 1) void encoder_kernel(
    const float* __restrict__ X,
    const float* __restrict__ Wih_f, const float* __restrict__ Whh_f, const float* __restrict__ b_f,
    const float* __restrict__ Wih_b, const float* __restrict__ Whh_b, const float* __restrict__ b_b,
    float* __restrict__ a, unsigned int* __restrict__ bar,
    unsigned short* __restrict__ a_hi)
{
    extern __shared__ unsigned char smem_raw[];
    unsigned short* Wh  = (unsigned short*)smem_raw;
    unsigned short* Wl  = (unsigned short*)smem_raw + WL_OFF;
    unsigned short* Ahh = (unsigned short*)smem_raw + AH_OFF;
    unsigned short* All = (unsigned short*)smem_raw + AL_OFF;
    float* Pre = (float*)(smem_raw + (size_t)PRE_OFF_US * 2);   // [32][68]
    float* bsh = Pre + 32 * 68;                                  // [64]

    const int tid = threadIdx.x;
    const int xcd = blockIdx.x & 7;
    const int sub = (blockIdx.x >> 3) & 1;
    const int jb  = blockIdx.x >> 4;        // 0..15
    const int dir = sub;
    const int ig  = xcd;
    const int i0 = ig * 32;
    const int j0 = jb * 16;
    const int grp = dir * 8 + ig;
    const int myjb = jb;
    unsigned int* slots = bar + grp * 16;

    const float* __restrict__ Wih = dir ? Wih_b : Wih_f;
    const float* __restrict__ Whh = dir ? Whh_b : Whh_f;
    const float* __restrict__ bv  = dir ? b_b  : b_f;

    if (tid < 64) bsh[tid] = bv[(tid >> 4) * NA + j0 + (tid & 15)];

    {
        const int col = tid & 255;
        const int r0w = (tid >> 8) * 32;       // 0 or 32
        for (int r = r0w; r < r0w + 32; ++r) {
            int row = (r >> 4) * NA + j0 + (r & 15);
            unsigned short hi, lo;
            split_bf16(Whh[(size_t)row * NA + col], hi, lo);
            Wh[r * W_STR + col] = hi;
            Wl[r * W_STR + col] = lo;
            if (col < NF) {
                split_bf16(Wih[(size_t)row * NF + col], hi, lo);
                Wh[r * W_STR + 256 + col] = hi;
                Wl[r * W_STR + 256 + col] = lo;
            }
        }
    }

    {
        const int col = tid & 255;
        const int r0z = (tid >> 8) * 16;       // 0 or 16
        #pragma unroll 4
        for (int r = r0z; r < r0z + 16; ++r) {
            Ahh[r * A_STR + col] = 0;
            All[r * A_STR + col] = 0;
        }
    }

    {
        const int t0 = dir ? (TXN - 1) : 0;
        const int kx = tid & 127;
        const int rbase = tid >> 7;            // 0..3
        #pragma unroll 4
        for (int rr = 0; rr < 8; ++rr) {
            int r = rr * 4 + rbase;
            float v = X[((size_t)(i0 + r) * TXN + t0) * NF + kx];
            unsigned short hi, lo;
            split_bf16(v, hi, lo);
            Ahh[r * A_STR + 256 + kx] = hi;
            All[r * A_STR + 256 + kx] = lo;
        }
    }
    __syncthreads();

    float cC = 0.f;
    const int jl  = tid & 15;
    const int epr = tid >> 4;

    const int lane = tid & 63;
    const int wv   = tid >> 6;
    const int rt   = wv >> 1;
    const int g0   = (wv & 1) * 2;
    const int ln   = lane & 15;
    const int quad = lane >> 4;
    const unsigned short* pAh = Ahh + (rt * 16 + ln) * A_STR + quad * 8;
    const unsigned short* pAl = All + (rt * 16 + ln) * A_STR + quad * 8;
    const unsigned short* pW0h = Wh + (g0 * 16 + ln) * W_STR + quad * 8;
    const unsigned short* pW0l = Wl + (g0 * 16 + ln) * W_STR + quad * 8;
    const unsigned short* pW1h = pW0h + 16 * W_STR;
    const unsigned short* pW1l = pW0l + 16 * W_STR;

    for (int step = 0; step < TXN; ++step) {
        const int t = dir ? (TXN - 1 - step) : step;

        f32x4 a0e = {0.f,0.f,0.f,0.f}, a0o = {0.f,0.f,0.f,0.f};
        f32x4 a1e = {0.f,0.f,0.f,0.f}, a1o = {0.f,0.f,0.f,0.f};

        if (tid < 256) {
            #pragma unroll
            for (int k4 = 0; k4 < 4; ++k4) {
                const int kc = 8 + k4;
                bf16x8 fah = *(const bf16x8*)(pAh + kc * 32);
                bf16x8 fal = *(const bf16x8*)(pAl + kc * 32);
                bf16x8 w0h = *(const bf16x8*)(pW0h + kc * 32);
                bf16x8 w0l = *(const bf16x8*)(pW0l + kc * 32);
                bf16x8 w1h = *(const bf16x8*)(pW1h + kc * 32);
                bf16x8 w1l = *(const bf16x8*)(pW1l + kc * 32);
                if ((kc & 1) == 0) {
                    a0e = __builtin_amdgcn_mfma_f32_16x16x32_bf16(fal, w0h, a0e, 0, 0, 0);
                    a0e = __builtin_amdgcn_mfma_f32_16x16x32_bf16(fah, w0l, a0e, 0, 0, 0);
                    a0e = __builtin_amdgcn_mfma_f32_16x16x32_bf16(fah, w0h, a0e, 0, 0, 0);
                    a1e = __builtin_amdgcn_mfma_f32_16x16x32_bf16(fal, w1h, a1e, 0, 0, 0);
                    a1e = __builtin_amdgcn_mfma_f32_16x16x32_bf16(fah, w1l, a1e, 0, 0, 0);
                    a1e = __builtin_amdgcn_mfma_f32_16x16x32_bf16(fah, w1h, a1e, 0, 0, 0);
                } else {
                    a0o = __builtin_amdgcn_mfma_f32_16x16x32_bf16(fal, w0h, a0o, 0, 0, 0);
                    a0o = __builtin_amdgcn_mfma_f32_16x16x32_bf16(fah, w0l, a0o, 0, 0, 0);
                    a0o = __builtin_amdgcn_mfma_f32_16x16x32_bf16(fah, w0h, a0o, 0, 0, 0);
                    a1o = __builtin_amdgcn_mfma_f32_16x16x32_bf16(fal, w1h, a1o, 0, 0, 0);
                    a1o = __builtin_amdgcn_mfma_f32_16x16x32_bf16(fah, w1l, a1o, 0, 0, 0);
                    a1o = __builtin_amdgcn_mfma_f32_16x16x32_bf16(fah, w1h, a1o, 0, 0, 0);
                }
            }
        } else if (step != 0) {
            const int tprev = dir ? (t + 1) : (t - 1);
            const int colh = tid & 255;
            const int jw = colh >> 4;
            while (flag_ld(&slots[jw]) < (unsigned)step) {}
            float hv[32];
            #pragma unroll
            for (int r = 0; r < 32; ++r) {
                hv[r] = agent_ld(&a[(((size_t)(i0 + r) * TXN + tprev) << 9) + dir * NA + colh]);
            }
            #pragma unroll
            for (int r = 0; r < 32; ++r) {
                unsigned short hi, lo;
                split_bf16(hv[r], hi, lo);
                Ahh[r * A_STR + colh] = hi;
                All[r * A_STR + colh] = lo;
            }
        }
        __syncthreads();

        if (tid < 256) {
            #pragma unroll
            for (int kp = 0; kp < 4; ++kp) {
                {
                    const int kc = kp * 2;
                    bf16x8 fah = *(const bf16x8*)(pAh + kc * 32);
                    bf16x8 fal = *(const bf16x8*)(pAl + kc * 32);
                    bf16x8 w0h = *(const bf16x8*)(pW0h + kc * 32);
                    bf16x8 w0l = *(const bf16x8*)(pW0l + kc * 32);
                    bf16x8 w1h = *(const bf16x8*)(pW1h + kc * 32);
                    bf16x8 w1l = *(const bf16x8*)(pW1l + kc * 32);
                    a0e = __builtin_amdgcn_mfma_f32_16x16x32_bf16(fal, w0h, a0e, 0, 0, 0);
                    a0e = __builtin_amdgcn_mfma_f32_16x16x32_bf16(fah, w0l, a0e, 0, 0, 0);
                    a0e = __builtin_amdgcn_mfma_f32_16x16x32_bf16(fah, w0h, a0e, 0, 0, 0);
                    a1e = __builtin_amdgcn_mfma_f32_16x16x32_bf16(fal, w1h, a1e, 0, 0, 0);
                    a1e = __builtin_amdgcn_mfma_f32_16x16x32_bf16(fah, w1l, a1e, 0, 0, 0);
                    a1e = __builtin_amdgcn_mfma_f32_16x16x32_bf16(fah, w1h, a1e, 0, 0, 0);
                }
                {
                    const int kc = kp * 2 + 1;
                    bf16x8 fah = *(const bf16x8*)(pAh + kc * 32);
                    bf16x8 fal = *(const bf16x8*)(pAl + kc * 32);
                    bf16x8 w0h = *(const bf16x8*)(pW0h + kc * 32);
                    bf16x8 w0l = *(const bf16x8*)(pW0l + kc * 32);
                    bf16x8 w1h = *(const bf16x8*)(pW1h + kc * 32);
                    bf16x8 w1l = *(const bf16x8*)(pW1l + kc * 32);
                    a0o = __builtin_amdgcn_mfma_f32_16x16x32_bf16(fal, w0h, a0o, 0, 0, 0);
                    a0o = __builtin_amdgcn_mfma_f32_16x16x32_bf16(fah, w0l, a0o, 0, 0, 0);
                    a0o = __builtin_amdgcn_mfma_f32_16x16x32_bf16(fah, w0h, a0o, 0, 0, 0);
                    a1o = __builtin_amdgcn_mfma_f32_16x16x32_bf16(fal, w1h, a1o, 0, 0, 0);
                    a1o = __builtin_amdgcn_mfma_f32_16x16x32_bf16(fah, w1l, a1o, 0, 0, 0);
                    a1o = __builtin_amdgcn_mfma_f32_16x16x32_bf16(fah, w1h, a1o, 0, 0, 0);
                }
            }
            #pragma unroll
            for (int reg = 0; reg < 4; ++reg) {
                int prow = rt * 16 + quad * 4 + reg;
                Pre[prow * 68 + g0 * 16 + ln]       = a0e[reg] + a0o[reg];
                Pre[prow * 68 + (g0 + 1) * 16 + ln] = a1e[reg] + a1o[reg];
            }
        }
        __syncthreads();

        {
            float gi = fsigmoid(Pre[epr * 68 +      jl] + bsh[jl]);
            float gf = fsigmoid(Pre[epr * 68 + 16 + jl] + bsh[16 + jl]);
            float gg = ftanh  (Pre[epr * 68 + 32 + jl] + bsh[32 + jl]);
            float go = fsigmoid(Pre[epr * 68 + 48 + jl] + bsh[48 + jl]);
            cC = gf * cC + gi * gg;
            float h = go * ftanh(cC);
            size_t ai = (((size_t)(i0 + epr) * TXN + t) << 9) + dir * NA + j0 + jl;
            agent_st(&a[ai], h);
            if (a_hi) {
                __hip_bfloat16 hb = __float2bfloat16(h);
                a_hi[ai] = *reinterpret_cast<unsigned short*>(&hb);
            }
        }

        if (step != TXN - 1) {
            __syncthreads();
            if (tid == 0) flag_st(&slots[myjb], (unsigned)(step + 1));
            {
                const int tn = dir ? (t - 1) : (t + 1);
                const int kx = tid & 127;
                const int rbase = tid >> 7;
                #pragma unroll 4
                for (int rr = 0; rr < 8; ++rr) {
                    int r = rr * 4 + rbase;
                    float v = X[((size_t)(i0 + r) * TXN + tn) * NF + kx];
                    unsigned short hi, lo;
                    split_bf16(v, hi, lo);
                    Ahh[r * A_STR + 256 + kx] = hi;
                    All[r * A_STR + 256 + kx] = lo;
                }
            }
            __syncthreads();
        }
    }
}

// ---------------------------------------------------------------------------
// Weight split kernels.
// ---------------------------------------------------------------------------
__global__ __launch_bounds__(256) void wsplit_cat(
    const float* __restrict__ Wc_ih, const float* __restrict__ Wc_hh,
    unsigned short* __restrict__ Wh, unsigned short* __restrict__ Wl)
{
    int idx = blockIdx.x * 256 + threadIdx.x;
    int r = idx >> 10, k = idx & 1023;
    float v = (k < 512) ? Wc_ih[(size_t)r * 512 + k] : Wc_hh[(size_t)r * 512 + (k - 512)];
    unsigned short hi, lo;
    split_bf16(v, hi, lo);
    Wh[idx] = hi; Wl[idx] = lo;
}

__global__ __launch_bounds__(256) void wsplit_fc(
    const float* __restrict__ Wfc,
    unsigned short* __restrict__ Wh, unsigned short* __restrict__ Wl)
{
    int idx = blockIdx.x * 256 + threadIdx.x;
    unsigned short hi, lo;
    split_bf16(Wfc[idx], hi, lo);
    Wh[idx] = hi; Wl[idx] = lo;
}

// ---------------------------------------------------------------------------
// Tall-skinny: aW1 = a @ W1[:, :512]^T + b1   (verified)
// ---------------------------------------------------------------------------
__global__ __launch_bounds__(256) void attn_prep(
    const float* __restrict__ a, const float* __restrict__ W1,
    const float* __restrict__ b1, float* __restrict__ aW1)
{
    __shared__ float Wsh[10][516];
    __shared__ float red[64][10][4];
    const int tid = threadIdx.x;
    for (int idx = tid; idx < 10 * 512; idx += 256) {
        int o = idx >> 9, k = idx & 511;
        Wsh[o][k] = W1[o * 1024 + k];
    }
    __syncthreads();
    const int r = tid >> 2, kq = tid & 3;
    const float* ar = a + ((size_t)blockIdx.x * 64 + r) * 512 + kq * 128;
    float acc[10] = {};
    for (int k = 0; k < 128; k += 4) {
        float4 v = *(const float4*)&ar[k];
        #pragma unroll
        for (int o = 0; o < 10; ++o) {
            float4 w = *(const float4*)&Wsh[o][kq * 128 + k];
            acc[o] += v.x * w.x + v.y * w.y + v.z * w.z + v.w * w.w;
        }
    }
    #pragma unroll
    for (int o = 0; o < 10; ++o) red[r][o][kq] = acc[o];
    __syncthreads();
    for (int idx = tid; idx < 640; idx += 256) {
        int rr = idx / 10, o = idx % 10;
        float s = red[rr][o][0] + red[rr][o][1] + red[rr][o][2] + red[rr][o][3] + b1[o];
        aW1[((size_t)blockIdx.x * 64 + rr) * 10 + o] = s;
    }
}

// ---------------------------------------------------------------------------
// PERSISTENT decoder: whole ty loop in one cooperative kernel, NO global
// barrier — producer/consumer flags (encoder's proven pattern). Block b:
//   phase A: attn row i=b (verified R11 bf16-ctx body; s via agent_ld)
//   phase B: gates tile (b&7, b>>3) (verified body; xcat/s via agent atomics;
//            c held in 2 registers — constant block->tile mapping)
// Flags (cumulative): xdone[g] += 1 per A of row-group g; sdone[g] += 1 per
// B of tile-row-group g. A(ty) waits sdone[i>>5] >= 32*ty (also closes the
// xcat WAR: those ARE the readers of row i). B(ty) waits xdone[b&7] >=
// 32*(ty+1) and sdone[b&7] >= 32*ty.
// ---------------------------------------------------------------------------
__global__ __launch_bounds__(256, 1) void decoder_kernel(
    const float* __restrict__ aW1,
    const float* __restrict__ W1,
    const float* __restrict__ W2,
    const float* __restrict__ b2,
    const unsigned short* __restrict__ a_hi,
    float* __restrict__ xcat,
    const unsigned short* __restrict__ Wch,
    const unsigned short* __restrict__ Wcl,
    const float* __restrict__ bc,
    float* __restrict__ S_all,
    const float* __restrict__ zbuf,
    unsigned int* __restrict__ sdone,
    unsigned int* __restrict__ xdone)
{
    extern __shared__ unsigned char smem_raw[];
    // gates overlay (verified layout)
    unsigned short* Wh = (unsigned short*)smem_raw + D_WH;
    unsigned short* Wl = (unsigned short*)smem_raw + D_WL;
    unsigned short* Ah = (unsigned short*)smem_raw + D_AH;
    unsigned short* Al = (unsigned short*)smem_raw + D_AL;
    float* Pre = (float*)(smem_raw + (size_t)D_PRE_US * 2);   // [32][68]
    float* bsh = Pre + 32 * 68;                                // [64]
    // attn overlay — first ~11 KB, inside the gates W region (disjoint in time)
    float* al    = (float*)smem_raw;           // [256]
    float* red   = al + 256;                   // [256]
    float* sred  = red + 256;                  // [160]
    float* sh_s  = sred + 160;                 // [10]
    float* sh_w2 = sh_s + 10;                  // [10]
    float* redc  = sh_w2 + 10;                 // [2048]

    const int tid = threadIdx.x;
    const int blk = blockIdx.x;
    const int agrp = blk >> 5;                 // attn row group
    const int bgrp = blk & 7;                  // gates tile row group
    const int gi0 = (blk & 7) * 32;
    const int gj0 = (blk >> 3) * 16;

    if (tid < 64) bsh[tid] = bc[(tid >> 4) * 512 + gj0 + (tid & 15)];

    const int lane = tid & 63;
    const int wv   = tid >> 6;
    const int rt   = wv >> 1;
    const int g0   = (wv & 1) * 2;
    const int ln   = lane & 15;
    const int quad = lane >> 4;
    const unsigned short* pAh = Ah + (rt * 16 + ln) * D_STR + quad * 8;
    const unsigned short* pAl = Al + (rt * 16 + ln) * D_STR + quad * 8;
    const unsigned short* pW0h = Wh + (g0 * 16 + ln) * D_STR + quad * 8;
    const unsigned short* pW0l = Wl + (g0 * 16 + ln) * D_STR + quad * 8;
    const unsigned short* pW1h = pW0h + 16 * D_STR;
    const unsigned short* pW1l = pW0l + 16 * D_STR;
    const int rW = tid >> 2;
    const int qW = (tid & 3) * 64;
    const int rowg = (rW >> 4) * 512 + gj0 + (rW & 15);

    // c-state in registers (block->tile mapping constant across ty)
    const int jl = tid & 15;
    const int iA = (tid >> 4) * 2;
    float c0r = 0.f, c1r = 0.f;

    for (int ty = 0; ty < TYN; ++ty) {
        const float* sprev = (ty == 0) ? zbuf : (S_all + (size_t)(ty - 1) * 512);
        const int spstr    = (ty == 0) ? 512 : (TYN * 512);
        float* sout        = S_all + (size_t)ty * 512;
        const int sostr    = TYN * 512;

        // ================ Phase A: attention (row i = blk) ================
        {
            const int i = blk;
            if (ty != 0) {
                const unsigned need = 32u * (unsigned)ty;
                while (flag_ld(&sdone[agrp]) < need) {}
                __builtin_amdgcn_sched_barrier(0);
            }

            if (tid < 160) {
                int o = tid >> 4, part = tid & 15;
                const float* srow = sprev + (size_t)i * spstr;
                const float* wrow = W1 + o * 1024 + 512;
                float p = 0.f;
                for (int k = part; k < 512; k += 16) p += agent_ld(&srow[k]) * wrow[k];
                sred[tid] = p;
            }
            __syncthreads();
            if (tid < 10) {
                float v = 0.f;
                #pragma unroll
                for (int p = 0; p < 16; ++p) v += sred[tid * 16 + p];
                sh_s[tid] = v;
                sh_w2[tid] = W2[tid];
            }
            __syncthreads();

            float sum = b2[0];
            const float* ar = aW1 + ((size_t)i * TXN + tid) * 10;
            #pragma unroll
            for (int h = 0; h < 10; ++h) {
                float e = ftanh(ar[h] + sh_s[h]);
                sum += e * sh_w2[h];
            }
            float sc = fmaxf(sum, 0.f);

            red[tid] = sc;
            __syncthreads();
            for (int s = 128; s > 0; s >>= 1) {
                if (tid < s) red[tid] = fmaxf(red[tid], red[tid + s]);
                __syncthreads();
            }
            float mx = red[0];
            __syncthreads();
            float p = __expf(sc - mx);
            red[tid] = p;
            __syncthreads();
            for (int s = 128; s > 0; s >>= 1) {
                if (tid < s) red[tid] += red[tid + s];
                __syncthreads();
            }
            float inv = 1.f / red[0];
            al[tid] = p * inv;
            __syncthreads();

            // ctx from bf16 plane (verified R11 body)
            const int q  = tid & 63;
            const int ph = tid >> 6;
            const unsigned short* abase = a_hi + ((size_t)i * TXN) * NS + q * 8;
            float acc[8] = {0.f,0.f,0.f,0.f,0.f,0.f,0.f,0.f};
            #pragma unroll 8
            for (int t = ph; t < TXN; t += 4) {
                float w = al[t];
                u16x8 v = *(const u16x8*)(abase + (size_t)t * NS);
                #pragma unroll
                for (int e = 0; e < 8; ++e) {
                    unsigned u = ((unsigned)v[e]) << 16;
                    acc[e] = fmaf(w, __uint_as_float(u), acc[e]);
                }
            }
            #pragma unroll
            for (int e = 0; e < 8; ++e) redc[tid * 8 + e] = acc[e];
            __syncthreads();
            if (tid < 64) {
                #pragma unroll
                for (int e = 0; e < 8; ++e) {
                    float s = redc[tid * 8 + e] + redc[(64 + tid) * 8 + e]
                            + redc[(128 + tid) * 8 + e] + redc[(192 + tid) * 8 + e];
                    agent_st(&xcat[(size_t)i * 512 + tid * 8 + e], s);
                }
            }
            __syncthreads();   // drain xcat stores before the flag bump
            if (tid == 0) atomicAdd(&xdone[agrp], 1u);
        }

        // ================ Phase B: gates tile (gi0, gj0) ==================
        {
            const unsigned needx = 32u * (unsigned)(ty + 1);
            while (flag_ld(&xdone[bgrp]) < needx) {}
            if (ty != 0) {
                const unsigned needs = 32u * (unsigned)ty;
                while (flag_ld(&sdone[bgrp]) < needs) {}
            }
            __builtin_amdgcn_sched_barrier(0);

            f32x4 a0 = {0.f,0.f,0.f,0.f}, a1 = {0.f,0.f,0.f,0.f};

            for (int ch = 0; ch < 4; ++ch) {
                const int kc0 = ch * 256;
                __syncthreads();
                #pragma unroll 8
                for (int r = 0; r < 32; ++r) {
                    float v;
                    if (ch < 2) v = agent_ld(&xcat[(size_t)(gi0 + r) * 512 + kc0 + tid]);
                    else        v = agent_ld(&sprev[(size_t)(gi0 + r) * spstr + (kc0 - 512) + tid]);
                    unsigned short hi, lo;
                    split_bf16(v, hi, lo);
                    Ah[r * D_STR + tid] = hi;
                    Al[r * D_STR + tid] = lo;
                }
                {
                    const size_t base = (size_t)rowg * 1024 + kc0 + qW;
                    #pragma unroll
                    for (int i = 0; i < 8; ++i) {
                        *(bf16x8*)&Wh[rW * D_STR + qW + i * 8] = *(const bf16x8*)&Wch[base + i * 8];
                        *(bf16x8*)&Wl[rW * D_STR + qW + i * 8] = *(const bf16x8*)&Wcl[base + i * 8];
                    }
                }
                __syncthreads();
                #pragma unroll
                for (int kc = 0; kc < 8; ++kc) {
                    bf16x8 fah = *(const bf16x8*)(pAh + kc * 32);
                    bf16x8 fal = *(const bf16x8*)(pAl + kc * 32);
                    bf16x8 w0h = *(const bf16x8*)(pW0h + kc * 32);
                    bf16x8 w0l = *(const bf16x8*)(pW0l + kc * 32);
                    bf16x8 w1h = *(const bf16x8*)(pW1h + kc * 32);
                    bf16x8 w1l = *(const bf16x8*)(pW1l + kc * 32);
                    a0 = __builtin_amdgcn_mfma_f32_16x16x32_bf16(fal, w0h, a0, 0, 0, 0);
                    a0 = __builtin_amdgcn_mfma_f32_16x16x32_bf16(fah, w0l, a0, 0, 0, 0);
                    a0 = __builtin_amdgcn_mfma_f32_16x16x32_bf16(fah, w0h, a0, 0, 0, 0);
                    a1 = __builtin_amdgcn_mfma_f32_16x16x32_bf16(fal, w1h, a1, 0, 0, 0);
                    a1 = __builtin_amdgcn_mfma_f32_16x16x32_bf16(fah, w1l, a1, 0, 0, 0);
                    a1 = __builtin_amdgcn_mfma_f32_16x16x32_bf16(fah, w1h, a1, 0, 0, 0);
                }
            }
            __syncthreads();
            #pragma unroll
            for (int reg = 0; reg < 4; ++reg) {
                int prow = rt * 16 + quad * 4 + reg;
                Pre[prow * 68 + g0 * 16 + ln]       = a0[reg];
                Pre[prow * 68 + (g0 + 1) * 16 + ln] = a1[reg];
            }
            __syncthreads();

            #pragma unroll
            for (int rr = 0; rr < 2; ++rr) {
                int r = iA + rr;
                float gi = fsigmoid(Pre[r * 68 +      jl] + bsh[jl]);
                float gf = fsigmoid(Pre[r * 68 + 16 + jl] + bsh[16 + jl]);
                float gg = ftanh  (Pre[r * 68 + 32 + jl] + bsh[32 + jl]);
                float go = fsigmoid(Pre[r * 68 + 48 + jl] + bsh[48 + jl]);
                float cprev = rr ? c1r : c0r;
                float cn = gf * cprev + gi * gg;
                if (rr) c1r = cn; else c0r = cn;
                agent_st(&sout[(size_t)(gi0 + r) * sostr + gj0 + jl], go * ftanh(cn));
            }
            __syncthreads();   // drain s stores before the flag bump
            if (tid == 0) atomicAdd(&sdone[bgrp], 1u);
        }
    }
}

// ---------------------------------------------------------------------------
// Fallback attention kernel (fp32 ctx) — verified.
// ---------------------------------------------------------------------------
__global__ __launch_bounds__(256) void attn_kernel(
    const float* __restrict__ aW1,
    const float* __restrict__ s_prev, int sp_stride,
    const float* __restrict__ W1,
    const float* __restrict__ W2,
    const float* __restrict__ b2,
    const float* __restrict__ a,
    float* __restrict__ xcat)
{
    __shared__ float sh_s[10];
    __shared__ float sh_w2[10];
    __shared__ float sred[160];
    __shared__ float red[256];
    __shared__ float al[256];
    __shared__ float4 ctxred[256];
    const int i = blockIdx.x;
    const int tid = threadIdx.x;

    if (tid < 160) {
        int o = tid >> 4, part = tid & 15;
        const float* srow = s_prev + (size_t)i * sp_stride;
        const float* wrow = W1 + o * 1024 + 512;
        float p = 0.f;
        for (int k = part; k < 512; k += 16) p += srow[k] * wrow[k];
        sred[tid] = p;
    }
    __syncthreads();
    if (tid < 10) {
        float v = 0.f;
        #pragma unroll
        for (int p = 0; p < 16; ++p) v += sred[tid * 16 + p];
        sh_s[tid] = v;
        sh_w2[tid] = W2[tid];
    }
    __syncthreads();

    float sum = b2[0];
    const float* ar = aW1 + ((size_t)i * TXN + tid) * 10;
    #pragma unroll
    for (int h = 0; h < 10; ++h) {
        float e = ftanh(ar[h] + sh_s[h]);
        sum += e * sh_w2[h];
    }
    float sc = fmaxf(sum, 0.f);

    red[tid] = sc;
    __syncthreads();
    for (int s = 128; s > 0; s >>= 1) {
        if (tid < s) red[tid] = fmaxf(red[tid], red[tid + s]);
        __syncthreads();
    }
    float mx = red[0];
    __syncthreads();
    float p = __expf(sc - mx);
    red[tid] = p;
    __syncthreads();
    for (int s = 128; s > 0; s >>= 1) {
        if (tid < s) red[tid] += red[tid + s];
        __syncthreads();
    }
    float inv = 1.f / red[0];
    al[tid] = p * inv;
    __syncthreads();

    const int half = tid >> 7;
    const int q    = tid & 127;
    const float* abase = a + (size_t)i * TXN * NS + q * 4;
    float4 acc = make_float4(0.f, 0.f, 0.f, 0.f);
    #pragma unroll 8
    for (int t = half; t < TXN; t += 2) {
        float w = al[t];
        float4 v = *(const float4*)&abase[(size_t)t * NS];
        acc.x += w * v.x; acc.y += w * v.y; acc.z += w * v.z; acc.w += w * v.w;
    }
    ctxred[tid] = acc;
    __syncthreads();
    if (tid < 128) {
        float4 e = ctxred[tid];
        float4 o = ctxred[tid + 128];
        float4 r4 = make_float4(e.x + o.x, e.y + o.y, e.z + o.z, e.w + o.w);
        *(float4*)&xcat[(size_t)i * 512 + tid * 4] = r4;
    }
}

// ---------------------------------------------------------------------------
// Fallback gates kernel — verified.
// ---------------------------------------------------------------------------
__global__ __launch_bounds__(256, 1) void gates_kernel(
    const float* __restrict__ xcat,
    const float* __restrict__ s_prev, int sp_stride,
    const unsigned short* __restrict__ Wch,
    const unsigned short* __restrict__ Wcl,
    const float* __restrict__ bc,
    float* __restrict__ c_buf,
    float* __restrict__ s_out, int so_stride)
{
    extern __shared__ unsigned char smem_raw[];
    unsigned short* Wh = (unsigned short*)smem_raw + D_WH;
    unsigned short* Wl = (unsigned short*)smem_raw + D_WL;
    unsigned short* Ah = (unsigned short*)smem_raw + D_AH;
    unsigned short* Al = (unsigned short*)smem_raw + D_AL;
    float* Pre = (float*)(smem_raw + (size_t)D_PRE_US * 2);
    float* bsh = Pre + 32 * 68;

    const int tid = threadIdx.x;
    const int i0 = blockIdx.x * 32;
    const int j0 = blockIdx.y * 16;

    if (tid < 64) bsh[tid] = bc[(tid >> 4) * 512 + j0 + (tid & 15)];

    const int lane = tid & 63;
    const int wv   = tid >> 6;
    const int rt   = wv >> 1;
    const int g0   = (wv & 1) * 2;
    const int ln   = lane & 15;
    const int quad = lane >> 4;
    const unsigned short* pAh = Ah + (rt * 16 + ln) * D_STR + quad * 8;
    const unsigned short* pAl = Al + (rt * 16 + ln) * D_STR + quad * 8;
    const unsigned short* pW0h = Wh + (g0 * 16 + ln) * D_STR + quad * 8;
    const unsigned short* pW0l = Wl + (g0 * 16 + ln) * D_STR + quad * 8;
    const unsigned short* pW1h = pW0h + 16 * D_STR;
    const unsigned short* pW1l = pW0l + 16 * D_STR;

    const int rW = tid >> 2;
    const int qW = (tid & 3) * 64;
    const int rowg = (rW >> 4) * 512 + j0 + (rW & 15);

    f32x4 a0 = {0.f,0.f,0.f,0.f}, a1 = {0.f,0.f,0.f,0.f};

    for (int ch = 0; ch < 4; ++ch) {
        const int kc0 = ch * 256;
        __syncthreads();
        #pragma unroll 8
        for (int r = 0; r < 32; ++r) {
            float v;
            if (ch < 2) v = xcat[(size_t)(i0 + r) * 512 + kc0 + tid];
            else        v = s_prev[(size_t)(i0 + r) * sp_stride + (kc0 - 512) + tid];
            unsigned short hi, lo;
            split_bf16(v, hi, lo);
            Ah[r * D_STR + tid] = hi;
            Al[r * D_STR + tid] = lo;
        }
        {
            const size_t base = (size_t)rowg * 1024 + kc0 + qW;
            #pragma unroll
            for (int i = 0; i < 8; ++i) {
                *(bf16x8*)&Wh[rW * D_STR + qW + i * 8] = *(const bf16x8*)&Wch[base + i * 8];
                *(bf16x8*)&Wl[rW * D_STR + qW + i * 8] = *(const bf16x8*)&Wcl[base + i * 8];
            }
        }
        __syncthreads();
        #pragma unroll
        for (int kc = 0; kc < 8; ++kc) {
            bf16x8 fah = *(const bf16x8*)(pAh + kc * 32);
            bf16x8 fal = *(const bf16x8*)(pAl + kc * 32);
            bf16x8 w0h = *(const bf16x8*)(pW0h + kc * 32);
            bf16x8 w0l = *(const bf16x8*)(pW0l + kc * 32);
            bf16x8 w1h = *(const bf16x8*)(pW1h + kc * 32);
            bf16x8 w1l = *(const bf16x8*)(pW1l + kc * 32);
            a0 = __builtin_amdgcn_mfma_f32_16x16x32_bf16(fal, w0h, a0, 0, 0, 0);
            a0 = __builtin_amdgcn_mfma_f32_16x16x32_bf16(fah, w0l, a0, 0, 0, 0);
            a0 = __builtin_amdgcn_mfma_f32_16x16x32_bf16(fah, w0h, a0, 0, 0, 0);
            a1 = __builtin_amdgcn_mfma_f32_16x16x32_bf16(fal, w1h, a1, 0, 0, 0);
            a1 = __builtin_amdgcn_mfma_f32_16x16x32_bf16(fah, w1l, a1, 0, 0, 0);
            a1 = __builtin_amdgcn_mfma_f32_16x16x32_bf16(fah, w1h, a1, 0, 0, 0);
        }
    }
    __syncthreads();
    #pragma unroll
    for (int reg = 0; reg < 4; ++reg) {
        int prow = rt * 16 + quad * 4 + reg;
        Pre[prow * 68 + g0 * 16 + ln]       = a0[reg];
        Pre[prow * 68 + (g0 + 1) * 16 + ln] = a1[reg];
    }
    __syncthreads();

    const int jl = tid & 15;
    const int iA = (tid >> 4) * 2;
    #pragma unroll
    for (int rr = 0; rr < 2; ++rr) {
        int r = iA + rr;
        float gi = fsigmoid(Pre[r * 68 +      jl] + bsh[jl]);
        float gf = fsigmoid(Pre[r * 68 + 16 + jl] + bsh[16 + jl]);
        float gg = ftanh  (Pre[r * 68 + 32 + jl] + bsh[32 + jl]);
        float go = fsigmoid(Pre[r * 68 + 48 + jl] + bsh[48 + jl]);
        size_t ci = (size_t)(i0 + r) * 512 + j0 + jl;
        float cn = gf * c_buf[ci] + gi * gg;
        c_buf[ci] = cn;
        s_out[(size_t)(i0 + r) * so_stride + j0 + jl] = go * ftanh(cn);
    }
}

// ---------------------------------------------------------------------------
// Logits GEMM — verified.
// ---------------------------------------------------------------------------
__global__ __launch_bounds__(256, 1) void logits_kernel(
    const float* __restrict__ S, int s_stride,
    const unsigned short* __restrict__ Wfh,
    const unsigned short* __restrict__ Wfl,
    const float* __restrict__ bfc,
    float* __restrict__ out, int o_stride, int o_off)
{
    extern __shared__ unsigned char smem_raw[];
    unsigned short* Wh = (unsigned short*)smem_raw + D_WH;
    unsigned short* Wl = (unsigned short*)smem_raw + D_WL;
    unsigned short* Ah = (unsigned short*)smem_raw + D_AH;
    unsigned short* Al = (unsigned short*)smem_raw + D_AL;

    const int tid = threadIdx.x;
    const int i0 = blockIdx.x * 32;
    const int v0 = blockIdx.y * 64;

    const int lane = tid & 63;
    const int wv   = tid >> 6;
    const int rt   = wv >> 1;
    const int ct   = wv & 1;
    const int ln   = lane & 15;
    const int quad = lane >> 4;
    const unsigned short* pAh = Ah + (rt * 16 + ln) * D_STR + quad * 8;
    const unsigned short* pAl = Al + (rt * 16 + ln) * D_STR + quad * 8;
    const unsigned short* pW0h = Wh + (ct * 32 + ln) * D_STR + quad * 8;
    const unsigned short* pW0l = Wl + (ct * 32 + ln) * D_STR + quad * 8;
    const unsigned short* pW1h = pW0h + 16 * D_STR;
    const unsigned short* pW1l = pW0l + 16 * D_STR;

    const int rW = tid >> 2;
    const int qW = (tid & 3) * 64;

    f32x4 a0 = {0.f,0.f,0.f,0.f}, a1 = {0.f,0.f,0.f,0.f};

    for (int ch = 0; ch < 2; ++ch) {
        const int kc0 = ch * 256;
        __syncthreads();
        #pragma unroll 8
        for (int r = 0; r < 32; ++r) {
            float v = S[(size_t)(i0 + r) * s_stride + kc0 + tid];
            unsigned short hi, lo;
            split_bf16(v, hi, lo);
            Ah[r * D_STR + tid] = hi;
            Al[r * D_STR + tid] = lo;
        }
        {
            const size_t base = (size_t)(v0 + rW) * 512 + kc0 + qW;
            #pragma unroll
            for (int i = 0; i < 8; ++i) {
                *(bf16x8*)&Wh[rW * D_STR + qW + i * 8] = *(const bf16x8*)&Wfh[base + i * 8];
                *(bf16x8*)&Wl[rW * D_STR + qW + i * 8] = *(const bf16x8*)&Wfl[base + i * 8];
            }
        }
        __syncthreads();
        #pragma unroll
        for (int kc = 0; kc < 8; ++kc) {
            bf16x8 fah = *(const bf16x8*)(pAh + kc * 32);
            bf16x8 fal = *(const bf16x8*)(pAl + kc * 32);
            bf16x8 w0h = *(const bf16x8*)(pW0h + kc * 32);
            bf16x8 w0l = *(const bf16x8*)(pW0l + kc * 32);
            bf16x8 w1h = *(const bf16x8*)(pW1h + kc * 32);
            bf16x8 w1l = *(const bf16x8*)(pW1l + kc * 32);
            a0 = __builtin_amdgcn_mfma_f32_16x16x32_bf16(fal, w0h, a0, 0, 0, 0);
            a0 = __builtin_amdgcn_mfma_f32_16x16x32_bf16(fah, w0l, a0, 0, 0, 0);
            a0 = __builtin_amdgcn_mfma_f32_16x16x32_bf16(fah, w0h, a0, 0, 0, 0);
            a1 = __builtin_amdgcn_mfma_f32_16x16x32_bf16(fal, w1h, a1, 0, 0, 0);
            a1 = __builtin_amdgcn_mfma_f32_16x16x32_bf16(fah, w1l, a1, 0, 0, 0);
            a1 = __builtin_amdgcn_mfma_f32_16x16x32_bf16(fah, w1h, a1, 0, 0, 0);
        }
    }
    #pragma unroll
    for (int reg = 0; reg < 4; ++reg) {
        int row = i0 + rt * 16 + quad * 4 + reg;
        int col0 = v0 + ct * 32 + ln;
        out[(size_t)row * o_stride + o_off + col0]      = a0[reg] + bfc[col0];
        out[(size_t)row * o_stride + o_off + col0 + 16] = a1[reg] + bfc[col0 + 16];
    }
}

extern "C" void kernel_launch(void* const* d_in, const int* in_sizes, int n_in,
                              void* d_out, int out_size, void* d_ws, size_t ws_size,
                              hipStream_t stream)
{
    const float* X     = (const float*)d_in[0];
    const float* Wih_f = (const float*)d_in[1];
    const float* Whh_f = (const float*)d_in[2];
    const float* b_f   = (const float*)d_in[3];
    const float* Wih_b = (const float*)d_in[4];
    const float* Whh_b = (const float*)d_in[5];
    const float* b_b   = (const float*)d_in[6];
    const float* W1    = (const float*)d_in[7];
    const float* b1    = (const float*)d_in[8];
    const float* W2    = (const float*)d_in[9];
    const float* b2    = (const float*)d_in[10];
    const float* Wc_ih = (const float*)d_in[11];
    const float* Wc_hh = (const float*)d_in[12];
    const float* bc    = (const float*)d_in[13];
    const float* Wfc   = (const float*)d_in[14];
    const float* bfc   = (const float*)d_in[15];
    float* out = (float*)d_out;
    float* ws  = (float*)d_ws;

    // workspace layout (float offsets) — no overlaps:
    float* c_buf = ws;                    // [0 .. 131072)       memset 0 (fallback)
    float* zbuf  = ws + 131072;           // [131072 .. 262144)  memset 0 (s(0))
    float* sbufB = ws + 262144;           // fallback ping-pong; first 16 uints = decoder flags
    float* xcat  = ws + 393216;           // ctx (256x512)
    float* a     = ws + 524288;           // fp32 encoder output
    float* aW1   = ws + 34078720;
    unsigned short* Wch = (unsigned short*)(ws + 34734080);
    unsigned short* Wcl = (unsigned short*)(ws + 35782656);
    unsigned short* Wfh = (unsigned short*)(ws + 36831232);
    unsigned short* Wfl = (unsigned short*)(ws + 37093376);
    unsigned int* bar   = (unsigned int*)(ws + 37355520);     // 256 uints (encoder)
    float* S_all = ws + 37355776;         // 2560*512 — deferred only
    unsigned short* a_hi = (unsigned short*)(ws + 38666496);  // 64 MB bf16 plane
    const int deferred = (ws_size >= (size_t)38666496 * sizeof(float)) ? 1 : 0;
    const int bf16ok   = (ws_size >= (size_t)55443712 * sizeof(float)) ? 1 : 0;

    unsigned int* dflags = (unsigned int*)sbufB;   // [0..7]=sdone, [8..15]=xdone
    unsigned int* sdone = dflags;
    unsigned int* xdone = dflags + 8;

    static int attrs_set = 0;
    if (!attrs_set) {
        hipFuncSetAttribute(reinterpret_cast<const void*>(encoder_kernel),
                            hipFuncAttributeMaxDynamicSharedMemorySize, ENC_LDS_BYTES);
        hipFuncSetAttribute(reinterpret_cast<const void*>(decoder_kernel),
                            hipFuncAttributeMaxDynamicSharedMemorySize, DEC_LDS_BYTES);
        hipFuncSetAttribute(reinterpret_cast<const void*>(gates_kernel),
                            hipFuncAttributeMaxDynamicSharedMemorySize, DEC_LDS_BYTES);
        hipFuncSetAttribute(reinterpret_cast<const void*>(logits_kernel),
                            hipFuncAttributeMaxDynamicSharedMemorySize, DEC_LDS_BYTES);
        attrs_set = 1;
    }

    // zero c_buf + zbuf + decoder flags (contiguous) and encoder flags
    hipMemsetAsync(c_buf, 0, ((size_t)262144 + 16) * sizeof(float), stream);
    hipMemsetAsync(bar, 0, 256 * sizeof(unsigned int), stream);

    wsplit_cat<<<8192, 256, 0, stream>>>(Wc_ih, Wc_hh, Wch, Wcl);
    wsplit_fc<<<2048, 256, 0, stream>>>(Wfc, Wfh, Wfl);

    {
        unsigned short* ahi_arg = bf16ok ? a_hi : (unsigned short*)nullptr;
        void* args[] = { (void*)&X, (void*)&Wih_f, (void*)&Whh_f, (void*)&b_f,
                         (void*)&Wih_b, (void*)&Whh_b, (void*)&b_b, (void*)&a,
                         (void*)&bar, (void*)&ahi_arg };
        hipLaunchCooperativeKernel(reinterpret_cast<void*>(encoder_kernel),
                                   dim3(256), dim3(512), args, ENC_LDS_BYTES, stream);
    }

    attn_prep<<<1024, 256, 0, stream>>>(a, W1, b1, aW1);

    if (deferred && bf16ok) {
        // persistent flag-synchronized decoder: one launch for all TYN steps
        void* args[] = { (void*)&aW1, (void*)&W1, (void*)&W2, (void*)&b2,
                         (void*)&a_hi, (void*)&xcat, (void*)&Wch, (void*)&Wcl,
                         (void*)&bc, (void*)&S_all, (void*)&zbuf,
                         (void*)&sdone, (void*)&xdone };
        hipLaunchCooperativeKernel(reinterpret_cast<void*>(decoder_kernel),
                                   dim3(256), dim3(256), args, DEC_LDS_BYTES, stream);
        logits_kernel<<<dim3(80, 16), 256, DEC_LDS_BYTES, stream>>>(
            S_all, 512, Wfh, Wfl, bfc, out, VOCAB, 0);
    } else if (deferred) {
        for (int ty = 0; ty < TYN; ++ty) {
            const float* sprev; int spstr;
            if (ty == 0) { sprev = zbuf; spstr = 512; }
            else { sprev = S_all + (size_t)(ty - 1) * 512; spstr = TYN * 512; }
            float* sout = S_all + (size_t)ty * 512;
            const int sostr = TYN * 512;
            attn_kernel<<<256, 256, 0, stream>>>(aW1, sprev, spstr, W1, W2, b2, a, xcat);
            gates_kernel<<<dim3(8, 32), 256, DEC_LDS_BYTES, stream>>>(
                xcat, sprev, spstr, Wch, Wcl, bc, c_buf, sout, sostr);
        }
        logits_kernel<<<dim3(80, 16), 256, DEC_LDS_BYTES, stream>>>(
            S_all, 512, Wfh, Wfl, bfc, out, VOCAB, 0);
    } else {
        for (int ty = 0; ty < TYN; ++ty) {
            const float* sprev; int spstr;
            float* sout; int sostr;
            if (ty == 0) { sprev = zbuf; spstr = 512; }
            else { sprev = (ty & 1) ? sbufB : zbuf; spstr = 512; }
            sout = (ty & 1) ? zbuf : sbufB; sostr = 512;
            attn_kernel<<<256, 256, 0, stream>>>(aW1, sprev, spstr, W1, W2, b2, a, xcat);
            gates_kernel<<<dim3(8, 32), 256, DEC_LDS_BYTES, stream>>>(
                xcat, sprev, spstr, Wch, Wcl, bc, c_buf, sout, sostr);
            logits_kernel<<<dim3(8, 16), 256, DEC_LDS_BYTES, stream>>>(
                sout, 512, Wfh, Wfl, bfc, out, TYN * VOCAB, ty * VOCAB);
        }
    }
}

// Round 13
// 1826.334 us; speedup vs baseline: 1.1442x; 1.1442x over previous
//
#include <hip/hip_runtime.h>
#include <hip/hip_bf16.h>

#define TXN 256   // Tx
#define NA 256    // n_a
#define NF 128    // features
#define NS 512    // n_s
#define TYN 10
#define VOCAB 1024

// ---- encoder LDS layout (split-bf16 planes) — IDENTICAL to verified R4/R7 ----
#define A_STR 392
#define W_STR 392
#define WL_OFF (64 * W_STR)
#define AH_OFF (2 * 64 * W_STR)
#define AL_OFF (AH_OFF + 32 * A_STR)
#define PRE_OFF_US (AL_OFF + 32 * A_STR)
#define ENC_LDS_BYTES (150528 + 32 * 68 * 4 + 64 * 4)   // 159,488 B

// ---- decoder MFMA-GEMM LDS layout (ushort indices), K-chunk = 256 ----
#define D_STR 264                        // 256 + 8 pad
#define D_WH 0
#define D_WL (64 * D_STR)                // 16896
#define D_AH (2 * 64 * D_STR)            // 33792
#define D_AL (D_AH + 32 * D_STR)         // 42240
#define D_PRE_US (D_AL + 32 * D_STR)     // 50688 -> byte 101376
#define DEC_LDS_BYTES (101376 + 32 * 68 * 4 + 64 * 4)   // 110,336 B

typedef __attribute__((ext_vector_type(8))) short bf16x8;
typedef __attribute__((ext_vector_type(8))) unsigned short u16x8;
typedef __attribute__((ext_vector_type(4))) float f32x4;

__device__ __forceinline__ float fsigmoid(float x) { return 1.f / (1.f + __expf(-x)); }
__device__ __forceinline__ float ftanh(float x)    { return 1.f - 2.f / (1.f + __expf(2.f * x)); }

__device__ __forceinline__ void split_bf16(float v, unsigned short& hi, unsigned short& lo) {
    __hip_bfloat16 h = __float2bfloat16(v);
    float rem = v - __bfloat162float(h);
    __hip_bfloat16 l = __float2bfloat16(rem);
    hi = *reinterpret_cast<unsigned short*>(&h);
    lo = *reinterpret_cast<unsigned short*>(&l);
}

__device__ __forceinline__ float agent_ld(const float* p) {
    return __hip_atomic_load(p, __ATOMIC_RELAXED, __HIP_MEMORY_SCOPE_AGENT);
}
__device__ __forceinline__ void agent_st(float* p, float v) {
    __hip_atomic_store(p, v, __ATOMIC_RELAXED, __HIP_MEMORY_SCOPE_AGENT);
}
__device__ __forceinline__ unsigned flag_ld(const unsigned* p) {
    return __hip_atomic_load(p, __ATOMIC_RELAXED, __HIP_MEMORY_SCOPE_AGENT);
}
__device__ __forceinline__ void flag_st(unsigned* p, unsigned v) {
    __hip_atomic_store(p, v, __ATOMIC_RELAXED, __HIP_MEMORY_SCOPE_AGENT);
}

// ---------------------------------------------------------------------------
// Persistent bidirectional LSTM encoder — verified R7/R11 (XCD-local groups,
// wave-specialized h staging overlapped with x-MFMAs, bf16 a_hi side-store).
// ---------------------------------------------------------------------------
__global__ __launch_bounds__(512, 1) void encoder_kernel(
    const float* __restrict__ X,
    const float* __restrict__ Wih_f, const float* __restrict__ Whh_f, const float* __restrict__ b_f,
    const float* __restrict__ Wih_b, const float* __restrict__ Whh_b, const float* __restrict__ b_b,
    float* __restrict__ a, unsigned int* __restrict__ bar,
    unsigned short* __restrict__ a_hi)
{
    extern __shared__ unsigned char smem_raw[];
    unsigned short* Wh  = (unsigned short*)smem_raw;
    unsigned short* Wl  = (unsigned short*)smem_raw + WL_OFF;
    unsigned short* Ahh = (unsigned short*)smem_raw + AH_OFF;
    unsigned short* All = (unsigned short*)smem_raw + AL_OFF;
    float* Pre = (float*)(smem_raw + (size_t)PRE_OFF_US * 2);   // [32][68]
    float* bsh = Pre + 32 * 68;                                  // [64]

    const int tid = threadIdx.x;
    const int xcd = blockIdx.x & 7;
    const int sub = (blockIdx.x >> 3) & 1;
    const int jb  = blockIdx.x >> 4;        // 0..15
    const int dir = sub;
    const int ig  = xcd;
    const int i0 = ig * 32;
    const int j0 = jb * 16;
    const int grp = dir * 8 + ig;
    const int myjb = jb;
    unsigned int* slots = bar + grp * 16;

    const float* __restrict__ Wih = dir ? Wih_b : Wih_f;
    const float* __restrict__ Whh = dir ? Whh_b : Whh_f;
    const float* __restrict__ bv  = dir ? b_b  : b_f;

    if (tid < 64) bsh[tid] = bv[(tid >> 4) * NA + j0 + (tid & 15)];

    {
        const int col = tid & 255;
        const int r0w = (tid >> 8) * 32;       // 0 or 32
        for (int r = r0w; r < r0w + 32; ++r) {
            int row = (r >> 4) * NA + j0 + (r & 15);
            unsigned short hi, lo;
            split_bf16(Whh[(size_t)row * NA + col], hi, lo);
            Wh[r * W_STR + col] = hi;
            Wl[r * W_STR + col] = lo;
            if (col < NF) {
                split_bf16(Wih[(size_t)row * NF + col], hi, lo);
                Wh[r * W_STR + 256 + col] = hi;
                Wl[r * W_STR + 256 + col] = lo;
            }
        }
    }

    {
        const int col = tid & 255;
        const int r0z = (tid >> 8) * 16;       // 0 or 16
        #pragma unroll 4
        for (int r = r0z; r < r0z + 16; ++r) {
            Ahh[r * A_STR + col] = 0;
            All[r * A_STR + col] = 0;
        }
    }

    {
        const int t0 = dir ? (TXN - 1) : 0;
        const int kx = tid & 127;
        const int rbase = tid >> 7;            // 0..3
        #pragma unroll 4
        for (int rr = 0; rr < 8; ++rr) {
            int r = rr * 4 + rbase;
            float v = X[((size_t)(i0 + r) * TXN + t0) * NF + kx];
            unsigned short hi, lo;
            split_bf16(v, hi, lo);
            Ahh[r * A_STR + 256 + kx] = hi;
            All[r * A_STR + 256 + kx] = lo;
        }
    }
    __syncthreads();

    float cC = 0.f;
    const int jl  = tid & 15;
    const int epr = tid >> 4;

    const int lane = tid & 63;
    const int wv   = tid >> 6;
    const int rt   = wv >> 1;
    const int g0   = (wv & 1) * 2;
    const int ln   = lane & 15;
    const int quad = lane >> 4;
    const unsigned short* pAh = Ahh + (rt * 16 + ln) * A_STR + quad * 8;
    const unsigned short* pAl = All + (rt * 16 + ln) * A_STR + quad * 8;
    const unsigned short* pW0h = Wh + (g0 * 16 + ln) * W_STR + quad * 8;
    const unsigned short* pW0l = Wl + (g0 * 16 + ln) * W_STR + quad * 8;
    const unsigned short* pW1h = pW0h + 16 * W_STR;
    const unsigned short* pW1l = pW0l + 16 * W_STR;

    for (int step = 0; step < TXN; ++step) {
        const int t = dir ? (TXN - 1 - step) : step;

        f32x4 a0e = {0.f,0.f,0.f,0.f}, a0o = {0.f,0.f,0.f,0.f};
        f32x4 a1e = {0.f,0.f,0.f,0.f}, a1o = {0.f,0.f,0.f,0.f};

        if (tid < 256) {
            #pragma unroll
            for (int k4 = 0; k4 < 4; ++k4) {
                const int kc = 8 + k4;
                bf16x8 fah = *(const bf16x8*)(pAh + kc * 32);
                bf16x8 fal = *(const bf16x8*)(pAl + kc * 32);
                bf16x8 w0h = *(const bf16x8*)(pW0h + kc * 32);
                bf16x8 w0l = *(const bf16x8*)(pW0l + kc * 32);
                bf16x8 w1h = *(const bf16x8*)(pW1h + kc * 32);
                bf16x8 w1l = *(const bf16x8*)(pW1l + kc * 32);
                if ((kc & 1) == 0) {
                    a0e = __builtin_amdgcn_mfma_f32_16x16x32_bf16(fal, w0h, a0e, 0, 0, 0);
                    a0e = __builtin_amdgcn_mfma_f32_16x16x32_bf16(fah, w0l, a0e, 0, 0, 0);
                    a0e = __builtin_amdgcn_mfma_f32_16x16x32_bf16(fah, w0h, a0e, 0, 0, 0);
                    a1e = __builtin_amdgcn_mfma_f32_16x16x32_bf16(fal, w1h, a1e, 0, 0, 0);
                    a1e = __builtin_amdgcn_mfma_f32_16x16x32_bf16(fah, w1l, a1e, 0, 0, 0);
                    a1e = __builtin_amdgcn_mfma_f32_16x16x32_bf16(fah, w1h, a1e, 0, 0, 0);
                } else {
                    a0o = __builtin_amdgcn_mfma_f32_16x16x32_bf16(fal, w0h, a0o, 0, 0, 0);
                    a0o = __builtin_amdgcn_mfma_f32_16x16x32_bf16(fah, w0l, a0o, 0, 0, 0);
                    a0o = __builtin_amdgcn_mfma_f32_16x16x32_bf16(fah, w0h, a0o, 0, 0, 0);
                    a1o = __builtin_amdgcn_mfma_f32_16x16x32_bf16(fal, w1h, a1o, 0, 0, 0);
                    a1o = __builtin_amdgcn_mfma_f32_16x16x32_bf16(fah, w1l, a1o, 0, 0, 0);
                    a1o = __builtin_amdgcn_mfma_f32_16x16x32_bf16(fah, w1h, a1o, 0, 0, 0);
                }
            }
        } else if (step != 0) {
            const int tprev = dir ? (t + 1) : (t - 1);
            const int colh = tid & 255;
            const int jw = colh >> 4;
            while (flag_ld(&slots[jw]) < (unsigned)step) {}
            float hv[32];
            #pragma unroll
            for (int r = 0; r < 32; ++r) {
                hv[r] = agent_ld(&a[(((size_t)(i0 + r) * TXN + tprev) << 9) + dir * NA + colh]);
            }
            #pragma unroll
            for (int r = 0; r < 32; ++r) {
                unsigned short hi, lo;
                split_bf16(hv[r], hi, lo);
                Ahh[r * A_STR + colh] = hi;
                All[r * A_STR + colh] = lo;
            }
        }
        __syncthreads();

        if (tid < 256) {
            #pragma unroll
            for (int kp = 0; kp < 4; ++kp) {
                {
                    const int kc = kp * 2;
                    bf16x8 fah = *(const bf16x8*)(pAh + kc * 32);
                    bf16x8 fal = *(const bf16x8*)(pAl + kc * 32);
                    bf16x8 w0h = *(const bf16x8*)(pW0h + kc * 32);
                    bf16x8 w0l = *(const bf16x8*)(pW0l + kc * 32);
                    bf16x8 w1h = *(const bf16x8*)(pW1h + kc * 32);
                    bf16x8 w1l = *(const bf16x8*)(pW1l + kc * 32);
                    a0e = __builtin_amdgcn_mfma_f32_16x16x32_bf16(fal, w0h, a0e, 0, 0, 0);
                    a0e = __builtin_amdgcn_mfma_f32_16x16x32_bf16(fah, w0l, a0e, 0, 0, 0);
                    a0e = __builtin_amdgcn_mfma_f32_16x16x32_bf16(fah, w0h, a0e, 0, 0, 0);
                    a1e = __builtin_amdgcn_mfma_f32_16x16x32_bf16(fal, w1h, a1e, 0, 0, 0);
                    a1e = __builtin_amdgcn_mfma_f32_16x16x32_bf16(fah, w1l, a1e, 0, 0, 0);
                    a1e = __builtin_amdgcn_mfma_f32_16x16x32_bf16(fah, w1h, a1e, 0, 0, 0);
                }
                {
                    const int kc = kp * 2 + 1;
                    bf16x8 fah = *(const bf16x8*)(pAh + kc * 32);
                    bf16x8 fal = *(const bf16x8*)(pAl + kc * 32);
                    bf16x8 w0h = *(const bf16x8*)(pW0h + kc * 32);
                    bf16x8 w0l = *(const bf16x8*)(pW0l + kc * 32);
                    bf16x8 w1h = *(const bf16x8*)(pW1h + kc * 32);
                    bf16x8 w1l = *(const bf16x8*)(pW1l + kc * 32);
                    a0o = __builtin_amdgcn_mfma_f32_16x16x32_bf16(fal, w0h, a0o, 0, 0, 0);
                    a0o = __builtin_amdgcn_mfma_f32_16x16x32_bf16(fah, w0l, a0o, 0, 0, 0);
                    a0o = __builtin_amdgcn_mfma_f32_16x16x32_bf16(fah, w0h, a0o, 0, 0, 0);
                    a1o = __builtin_amdgcn_mfma_f32_16x16x32_bf16(fal, w1h, a1o, 0, 0, 0);
                    a1o = __builtin_amdgcn_mfma_f32_16x16x32_bf16(fah, w1l, a1o, 0, 0, 0);
                    a1o = __builtin_amdgcn_mfma_f32_16x16x32_bf16(fah, w1h, a1o, 0, 0, 0);
                }
            }
            #pragma unroll
            for (int reg = 0; reg < 4; ++reg) {
                int prow = rt * 16 + quad * 4 + reg;
                Pre[prow * 68 + g0 * 16 + ln]       = a0e[reg] + a0o[reg];
                Pre[prow * 68 + (g0 + 1) * 16 + ln] = a1e[reg] + a1o[reg];
            }
        }
        __syncthreads();

        {
            float gi = fsigmoid(Pre[epr * 68 +      jl] + bsh[jl]);
            float gf = fsigmoid(Pre[epr * 68 + 16 + jl] + bsh[16 + jl]);
            float gg = ftanh  (Pre[epr * 68 + 32 + jl] + bsh[32 + jl]);
            float go = fsigmoid(Pre[epr * 68 + 48 + jl] + bsh[48 + jl]);
            cC = gf * cC + gi * gg;
            float h = go * ftanh(cC);
            size_t ai = (((size_t)(i0 + epr) * TXN + t) << 9) + dir * NA + j0 + jl;
            agent_st(&a[ai], h);
            if (a_hi) {
                __hip_bfloat16 hb = __float2bfloat16(h);
                a_hi[ai] = *reinterpret_cast<unsigned short*>(&hb);
            }
        }

        if (step != TXN - 1) {
            __syncthreads();
            if (tid == 0) flag_st(&slots[myjb], (unsigned)(step + 1));
            {
                const int tn = dir ? (t - 1) : (t + 1);
                const int kx = tid & 127;
                const int rbase = tid >> 7;
                #pragma unroll 4
                for (int rr = 0; rr < 8; ++rr) {
                    int r = rr * 4 + rbase;
                    float v = X[((size_t)(i0 + r) * TXN + tn) * NF + kx];
                    unsigned short hi, lo;
                    split_bf16(v, hi, lo);
                    Ahh[r * A_STR + 256 + kx] = hi;
                    All[r * A_STR + 256 + kx] = lo;
                }
            }
            __syncthreads();
        }
    }
}

// ---------------------------------------------------------------------------
// Weight split kernels.
// ---------------------------------------------------------------------------
__global__ __launch_bounds__(256) void wsplit_cat(
    const float* __restrict__ Wc_ih, const float* __restrict__ Wc_hh,
    unsigned short* __restrict__ Wh, unsigned short* __restrict__ Wl)
{
    int idx = blockIdx.x * 256 + threadIdx.x;
    int r = idx >> 10, k = idx & 1023;
    float v = (k < 512) ? Wc_ih[(size_t)r * 512 + k] : Wc_hh[(size_t)r * 512 + (k - 512)];
    unsigned short hi, lo;
    split_bf16(v, hi, lo);
    Wh[idx] = hi; Wl[idx] = lo;
}

__global__ __launch_bounds__(256) void wsplit_fc(
    const float* __restrict__ Wfc,
    unsigned short* __restrict__ Wh, unsigned short* __restrict__ Wl)
{
    int idx = blockIdx.x * 256 + threadIdx.x;
    unsigned short hi, lo;
    split_bf16(Wfc[idx], hi, lo);
    Wh[idx] = hi; Wl[idx] = lo;
}

// ---------------------------------------------------------------------------
// Tall-skinny: aW1 = a @ W1[:, :512]^T + b1   (verified)
// ---------------------------------------------------------------------------
__global__ __launch_bounds__(256) void attn_prep(
    const float* __restrict__ a, const float* __restrict__ W1,
    const float* __restrict__ b1, float* __restrict__ aW1)
{
    __shared__ float Wsh[10][516];
    __shared__ float red[64][10][4];
    const int tid = threadIdx.x;
    for (int idx = tid; idx < 10 * 512; idx += 256) {
        int o = idx >> 9, k = idx & 511;
        Wsh[o][k] = W1[o * 1024 + k];
    }
    __syncthreads();
    const int r = tid >> 2, kq = tid & 3;
    const float* ar = a + ((size_t)blockIdx.x * 64 + r) * 512 + kq * 128;
    float acc[10] = {};
    for (int k = 0; k < 128; k += 4) {
        float4 v = *(const float4*)&ar[k];
        #pragma unroll
        for (int o = 0; o < 10; ++o) {
            float4 w = *(const float4*)&Wsh[o][kq * 128 + k];
            acc[o] += v.x * w.x + v.y * w.y + v.z * w.z + v.w * w.w;
        }
    }
    #pragma unroll
    for (int o = 0; o < 10; ++o) red[r][o][kq] = acc[o];
    __syncthreads();
    for (int idx = tid; idx < 640; idx += 256) {
        int rr = idx / 10, o = idx % 10;
        float s = red[rr][o][0] + red[rr][o][1] + red[rr][o][2] + red[rr][o][3] + b1[o];
        aW1[((size_t)blockIdx.x * 64 + rr) * 10 + o] = s;
    }
}

// ---------------------------------------------------------------------------
// Attention with bf16 ctx read — verified R11.
// ---------------------------------------------------------------------------
__global__ __launch_bounds__(256) void attn_bf16_kernel(
    const float* __restrict__ aW1,
    const float* __restrict__ s_prev, int sp_stride,
    const float* __restrict__ W1,
    const float* __restrict__ W2,
    const float* __restrict__ b2,
    const unsigned short* __restrict__ a_hi,
    float* __restrict__ xcat)
{
    __shared__ float sh_s[10];
    __shared__ float sh_w2[10];
    __shared__ float sred[160];
    __shared__ float red[256];
    __shared__ float al[256];
    __shared__ float redc[2048];   // [256][8]
    const int i = blockIdx.x;
    const int tid = threadIdx.x;

    if (tid < 160) {
        int o = tid >> 4, part = tid & 15;
        const float* srow = s_prev + (size_t)i * sp_stride;
        const float* wrow = W1 + o * 1024 + 512;
        float p = 0.f;
        for (int k = part; k < 512; k += 16) p += srow[k] * wrow[k];
        sred[tid] = p;
    }
    __syncthreads();
    if (tid < 10) {
        float v = 0.f;
        #pragma unroll
        for (int p = 0; p < 16; ++p) v += sred[tid * 16 + p];
        sh_s[tid] = v;
        sh_w2[tid] = W2[tid];
    }
    __syncthreads();

    float sum = b2[0];
    const float* ar = aW1 + ((size_t)i * TXN + tid) * 10;
    #pragma unroll
    for (int h = 0; h < 10; ++h) {
        float e = ftanh(ar[h] + sh_s[h]);
        sum += e * sh_w2[h];
    }
    float sc = fmaxf(sum, 0.f);

    red[tid] = sc;
    __syncthreads();
    for (int s = 128; s > 0; s >>= 1) {
        if (tid < s) red[tid] = fmaxf(red[tid], red[tid + s]);
        __syncthreads();
    }
    float mx = red[0];
    __syncthreads();
    float p = __expf(sc - mx);
    red[tid] = p;
    __syncthreads();
    for (int s = 128; s > 0; s >>= 1) {
        if (tid < s) red[tid] += red[tid + s];
        __syncthreads();
    }
    float inv = 1.f / red[0];
    al[tid] = p * inv;
    __syncthreads();

    const int q  = tid & 63;
    const int ph = tid >> 6;
    const unsigned short* abase = a_hi + ((size_t)i * TXN) * NS + q * 8;
    float acc[8] = {0.f,0.f,0.f,0.f,0.f,0.f,0.f,0.f};
    #pragma unroll 8
    for (int t = ph; t < TXN; t += 4) {
        float w = al[t];
        u16x8 v = *(const u16x8*)(abase + (size_t)t * NS);
        #pragma unroll
        for (int e = 0; e < 8; ++e) {
            unsigned u = ((unsigned)v[e]) << 16;
            acc[e] = fmaf(w, __uint_as_float(u), acc[e]);
        }
    }
    #pragma unroll
    for (int e = 0; e < 8; ++e) redc[tid * 8 + e] = acc[e];
    __syncthreads();
    if (tid < 64) {
        float s[8];
        #pragma unroll
        for (int e = 0; e < 8; ++e)
            s[e] = redc[tid * 8 + e] + redc[(64 + tid) * 8 + e]
                 + redc[(128 + tid) * 8 + e] + redc[(192 + tid) * 8 + e];
        *(float4*)&xcat[(size_t)i * 512 + tid * 8]     = make_float4(s[0], s[1], s[2], s[3]);
        *(float4*)&xcat[(size_t)i * 512 + tid * 8 + 4] = make_float4(s[4], s[5], s[6], s[7]);
    }
}

// ---------------------------------------------------------------------------
// Fallback attention kernel (fp32 ctx) — verified.
// ---------------------------------------------------------------------------
__global__ __launch_bounds__(256) void attn_kernel(
    const float* __restrict__ aW1,
    const float* __restrict__ s_prev, int sp_stride,
    const float* __restrict__ W1,
    const float* __restrict__ W2,
    const float* __restrict__ b2,
    const float* __restrict__ a,
    float* __restrict__ xcat)
{
    __shared__ float sh_s[10];
    __shared__ float sh_w2[10];
    __shared__ float sred[160];
    __shared__ float red[256];
    __shared__ float al[256];
    __shared__ float4 ctxred[256];
    const int i = blockIdx.x;
    const int tid = threadIdx.x;

    if (tid < 160) {
        int o = tid >> 4, part = tid & 15;
        const float* srow = s_prev + (size_t)i * sp_stride;
        const float* wrow = W1 + o * 1024 + 512;
        float p = 0.f;
        for (int k = part; k < 512; k += 16) p += srow[k] * wrow[k];
        sred[tid] = p;
    }
    __syncthreads();
    if (tid < 10) {
        float v = 0.f;
        #pragma unroll
        for (int p = 0; p < 16; ++p) v += sred[tid * 16 + p];
        sh_s[tid] = v;
        sh_w2[tid] = W2[tid];
    }
    __syncthreads();

    float sum = b2[0];
    const float* ar = aW1 + ((size_t)i * TXN + tid) * 10;
    #pragma unroll
    for (int h = 0; h < 10; ++h) {
        float e = ftanh(ar[h] + sh_s[h]);
        sum += e * sh_w2[h];
    }
    float sc = fmaxf(sum, 0.f);

    red[tid] = sc;
    __syncthreads();
    for (int s = 128; s > 0; s >>= 1) {
        if (tid < s) red[tid] = fmaxf(red[tid], red[tid + s]);
        __syncthreads();
    }
    float mx = red[0];
    __syncthreads();
    float p = __expf(sc - mx);
    red[tid] = p;
    __syncthreads();
    for (int s = 128; s > 0; s >>= 1) {
        if (tid < s) red[tid] += red[tid + s];
        __syncthreads();
    }
    float inv = 1.f / red[0];
    al[tid] = p * inv;
    __syncthreads();

    const int half = tid >> 7;
    const int q    = tid & 127;
    const float* abase = a + (size_t)i * TXN * NS + q * 4;
    float4 acc = make_float4(0.f, 0.f, 0.f, 0.f);
    #pragma unroll 8
    for (int t = half; t < TXN; t += 2) {
        float w = al[t];
        float4 v = *(const float4*)&abase[(size_t)t * NS];
        acc.x += w * v.x; acc.y += w * v.y; acc.z += w * v.z; acc.w += w * v.w;
    }
    ctxred[tid] = acc;
    __syncthreads();
    if (tid < 128) {
        float4 e = ctxred[tid];
        float4 o = ctxred[tid + 128];
        float4 r4 = make_float4(e.x + o.x, e.y + o.y, e.z + o.z, e.w + o.w);
        *(float4*)&xcat[(size_t)i * 512 + tid * 4] = r4;
    }
}

// ---------------------------------------------------------------------------
// Decoder gates GEMM + fused LSTM cell. 1D grid (256) with XCD-affinity
// swizzle: all 8 i-blocks sharing a W column-tile (same j0) have equal
// blockIdx%8 -> same XCD L2 -> W fetched once per XCD, not 8x.
// Tile work identical to verified kernel (pure index bijection).
// ---------------------------------------------------------------------------
__global__ __launch_bounds__(256, 1) void gates_kernel(
    const float* __restrict__ xcat,
    const float* __restrict__ s_prev, int sp_stride,
    const unsigned short* __restrict__ Wch,
    const unsigned short* __restrict__ Wcl,
    const float* __restrict__ bc,
    float* __restrict__ c_buf,
    float* __restrict__ s_out, int so_stride)
{
    extern __shared__ unsigned char smem_raw[];
    unsigned short* Wh = (unsigned short*)smem_raw + D_WH;
    unsigned short* Wl = (unsigned short*)smem_raw + D_WL;
    unsigned short* Ah = (unsigned short*)smem_raw + D_AH;
    unsigned short* Al = (unsigned short*)smem_raw + D_AL;
    float* Pre = (float*)(smem_raw + (size_t)D_PRE_US * 2);   // [32][68]
    float* bsh = Pre + 32 * 68;                                // [64]

    const int tid = threadIdx.x;
    // XCD-affinity decode: b = xcd + 8*(i + 8*(jb>>3)), jb = xcd + 8*(rest>>3)
    const int xcd  = blockIdx.x & 7;
    const int rest = blockIdx.x >> 3;          // 0..31
    const int i0 = (rest & 7) * 32;
    const int jb = xcd + ((rest >> 3) << 3);   // 0..31
    const int j0 = jb * 16;

    if (tid < 64) bsh[tid] = bc[(tid >> 4) * 512 + j0 + (tid & 15)];

    const int lane = tid & 63;
    const int wv   = tid >> 6;
    const int rt   = wv >> 1;
    const int g0   = (wv & 1) * 2;
    const int ln   = lane & 15;
    const int quad = lane >> 4;
    const unsigned short* pAh = Ah + (rt * 16 + ln) * D_STR + quad * 8;
    const unsigned short* pAl = Al + (rt * 16 + ln) * D_STR + quad * 8;
    const unsigned short* pW0h = Wh + (g0 * 16 + ln) * D_STR + quad * 8;
    const unsigned short* pW0l = Wl + (g0 * 16 + ln) * D_STR + quad * 8;
    const unsigned short* pW1h = pW0h + 16 * D_STR;
    const unsigned short* pW1l = pW0l + 16 * D_STR;

    const int rW = tid >> 2;
    const int qW = (tid & 3) * 64;
    const int rowg = (rW >> 4) * 512 + j0 + (rW & 15);

    f32x4 a0 = {0.f,0.f,0.f,0.f}, a1 = {0.f,0.f,0.f,0.f};

    for (int ch = 0; ch < 4; ++ch) {
        const int kc0 = ch * 256;
        __syncthreads();
        #pragma unroll 8
        for (int r = 0; r < 32; ++r) {
            float v;
            if (ch < 2) v = xcat[(size_t)(i0 + r) * 512 + kc0 + tid];
            else        v = s_prev[(size_t)(i0 + r) * sp_stride + (kc0 - 512) + tid];
            unsigned short hi, lo;
            split_bf16(v, hi, lo);
            Ah[r * D_STR + tid] = hi;
            Al[r * D_STR + tid] = lo;
        }
        {
            const size_t base = (size_t)rowg * 1024 + kc0 + qW;
            #pragma unroll
            for (int i = 0; i < 8; ++i) {
                *(bf16x8*)&Wh[rW * D_STR + qW + i * 8] = *(const bf16x8*)&Wch[base + i * 8];
                *(bf16x8*)&Wl[rW * D_STR + qW + i * 8] = *(const bf16x8*)&Wcl[base + i * 8];
            }
        }
        __syncthreads();
        #pragma unroll
        for (int kc = 0; kc < 8; ++kc) {
            bf16x8 fah = *(const bf16x8*)(pAh + kc * 32);
            bf16x8 fal = *(const bf16x8*)(pAl + kc * 32);
            bf16x8 w0h = *(const bf16x8*)(pW0h + kc * 32);
            bf16x8 w0l = *(const bf16x8*)(pW0l + kc * 32);
            bf16x8 w1h = *(const bf16x8*)(pW1h + kc * 32);
            bf16x8 w1l = *(const bf16x8*)(pW1l + kc * 32);
            a0 = __builtin_amdgcn_mfma_f32_16x16x32_bf16(fal, w0h, a0, 0, 0, 0);
            a0 = __builtin_amdgcn_mfma_f32_16x16x32_bf16(fah, w0l, a0, 0, 0, 0);
            a0 = __builtin_amdgcn_mfma_f32_16x16x32_bf16(fah, w0h, a0, 0, 0, 0);
            a1 = __builtin_amdgcn_mfma_f32_16x16x32_bf16(fal, w1h, a1, 0, 0, 0);
            a1 = __builtin_amdgcn_mfma_f32_16x16x32_bf16(fah, w1l, a1, 0, 0, 0);
            a1 = __builtin_amdgcn_mfma_f32_16x16x32_bf16(fah, w1h, a1, 0, 0, 0);
        }
    }
    __syncthreads();
    #pragma unroll
    for (int reg = 0; reg < 4; ++reg) {
        int prow = rt * 16 + quad * 4 + reg;
        Pre[prow * 68 + g0 * 16 + ln]       = a0[reg];
        Pre[prow * 68 + (g0 + 1) * 16 + ln] = a1[reg];
    }
    __syncthreads();

    const int jl = tid & 15;
    const int iA = (tid >> 4) * 2;
    #pragma unroll
    for (int rr = 0; rr < 2; ++rr) {
        int r = iA + rr;
        float gi = fsigmoid(Pre[r * 68 +      jl] + bsh[jl]);
        float gf = fsigmoid(Pre[r * 68 + 16 + jl] + bsh[16 + jl]);
        float gg = ftanh  (Pre[r * 68 + 32 + jl] + bsh[32 + jl]);
        float go = fsigmoid(Pre[r * 68 + 48 + jl] + bsh[48 + jl]);
        size_t ci = (size_t)(i0 + r) * 512 + j0 + jl;
        float cn = gf * c_buf[ci] + gi * gg;
        c_buf[ci] = cn;
        s_out[(size_t)(i0 + r) * so_stride + j0 + jl] = go * ftanh(cn);
    }
}

// ---------------------------------------------------------------------------
// Logits GEMM. 1D grid with XCD-affinity swizzle parameterized by ni
// (number of i-blocks): all ni blocks sharing a W tile have equal
// blockIdx%8 -> same XCD. b = xcd + 8*(i + ni*(vb>>3)), vb = xcd+8*(...).
// ---------------------------------------------------------------------------
__global__ __launch_bounds__(256, 1) void logits_kernel(
    const float* __restrict__ S, int s_stride, int ni,
    const unsigned short* __restrict__ Wfh,
    const unsigned short* __restrict__ Wfl,
    const float* __restrict__ bfc,
    float* __restrict__ out, int o_stride, int o_off)
{
    extern __shared__ unsigned char smem_raw[];
    unsigned short* Wh = (unsigned short*)smem_raw + D_WH;
    unsigned short* Wl = (unsigned short*)smem_raw + D_WL;
    unsigned short* Ah = (unsigned short*)smem_raw + D_AH;
    unsigned short* Al = (unsigned short*)smem_raw + D_AL;

    const int tid = threadIdx.x;
    const int xcd = blockIdx.x & 7;
    const int r8  = blockIdx.x >> 3;           // 0 .. 2*ni-1
    const int i0 = (r8 % ni) * 32;
    const int vb = xcd + ((r8 / ni) << 3);     // 0..15
    const int v0 = vb * 64;

    const int lane = tid & 63;
    const int wv   = tid >> 6;
    const int rt   = wv >> 1;
    const int ct   = wv & 1;
    const int ln   = lane & 15;
    const int quad = lane >> 4;
    const unsigned short* pAh = Ah + (rt * 16 + ln) * D_STR + quad * 8;
    const unsigned short* pAl = Al + (rt * 16 + ln) * D_STR + quad * 8;
    const unsigned short* pW0h = Wh + (ct * 32 + ln) * D_STR + quad * 8;
    const unsigned short* pW0l = Wl + (ct * 32 + ln) * D_STR + quad * 8;
    const unsigned short* pW1h = pW0h + 16 * D_STR;
    const unsigned short* pW1l = pW0l + 16 * D_STR;

    const int rW = tid >> 2;
    const int qW = (tid & 3) * 64;

    f32x4 a0 = {0.f,0.f,0.f,0.f}, a1 = {0.f,0.f,0.f,0.f};

    for (int ch = 0; ch < 2; ++ch) {
        const int kc0 = ch * 256;
        __syncthreads();
        #pragma unroll 8
        for (int r = 0; r < 32; ++r) {
            float v = S[(size_t)(i0 + r) * s_stride + kc0 + tid];
            unsigned short hi, lo;
            split_bf16(v, hi, lo);
            Ah[r * D_STR + tid] = hi;
            Al[r * D_STR + tid] = lo;
        }
        {
            const size_t base = (size_t)(v0 + rW) * 512 + kc0 + qW;
            #pragma unroll
            for (int i = 0; i < 8; ++i) {
                *(bf16x8*)&Wh[rW * D_STR + qW + i * 8] = *(const bf16x8*)&Wfh[base + i * 8];
                *(bf16x8*)&Wl[rW * D_STR + qW + i * 8] = *(const bf16x8*)&Wfl[base + i * 8];
            }
        }
        __syncthreads();
        #pragma unroll
        for (int kc = 0; kc < 8; ++kc) {
            bf16x8 fah = *(const bf16x8*)(pAh + kc * 32);
            bf16x8 fal = *(const bf16x8*)(pAl + kc * 32);
            bf16x8 w0h = *(const bf16x8*)(pW0h + kc * 32);
            bf16x8 w0l = *(const bf16x8*)(pW0l + kc * 32);
            bf16x8 w1h = *(const bf16x8*)(pW1h + kc * 32);
            bf16x8 w1l = *(const bf16x8*)(pW1l + kc * 32);
            a0 = __builtin_amdgcn_mfma_f32_16x16x32_bf16(fal, w0h, a0, 0, 0, 0);
            a0 = __builtin_amdgcn_mfma_f32_16x16x32_bf16(fah, w0l, a0, 0, 0, 0);
            a0 = __builtin_amdgcn_mfma_f32_16x16x32_bf16(fah, w0h, a0, 0, 0, 0);
            a1 = __builtin_amdgcn_mfma_f32_16x16x32_bf16(fal, w1h, a1, 0, 0, 0);
            a1 = __builtin_amdgcn_mfma_f32_16x16x32_bf16(fah, w1l, a1, 0, 0, 0);
            a1 = __builtin_amdgcn_mfma_f32_16x16x32_bf16(fah, w1h, a1, 0, 0, 0);
        }
    }
    #pragma unroll
    for (int reg = 0; reg < 4; ++reg) {
        int row = i0 + rt * 16 + quad * 4 + reg;
        int col0 = v0 + ct * 32 + ln;
        out[(size_t)row * o_stride + o_off + col0]      = a0[reg] + bfc[col0];
        out[(size_t)row * o_stride + o_off + col0 + 16] = a1[reg] + bfc[col0 + 16];
    }
}

extern "C" void kernel_launch(void* const* d_in, const int* in_sizes, int n_in,
                              void* d_out, int out_size, void* d_ws, size_t ws_size,
                              hipStream_t stream)
{
    const float* X     = (const float*)d_in[0];
    const float* Wih_f = (const float*)d_in[1];
    const float* Whh_f = (const float*)d_in[2];
    const float* b_f   = (const float*)d_in[3];
    const float* Wih_b = (const float*)d_in[4];
    const float* Whh_b = (const float*)d_in[5];
    const float* b_b   = (const float*)d_in[6];
    const float* W1    = (const float*)d_in[7];
    const float* b1    = (const float*)d_in[8];
    const float* W2    = (const float*)d_in[9];
    const float* b2    = (const float*)d_in[10];
    const float* Wc_ih = (const float*)d_in[11];
    const float* Wc_hh = (const float*)d_in[12];
    const float* bc    = (const float*)d_in[13];
    const float* Wfc   = (const float*)d_in[14];
    const float* bfc   = (const float*)d_in[15];
    float* out = (float*)d_out;
    float* ws  = (float*)d_ws;

    // workspace layout (float offsets) — no overlaps:
    float* c_buf = ws;                    // [0 .. 131072)       memset 0
    float* zbuf  = ws + 131072;           // [131072 .. 262144)  memset 0 (s(0))
    float* sbufB = ws + 262144;           // fallback ping-pong
    float* xcat  = ws + 393216;           // ctx (256x512)
    float* a     = ws + 524288;           // fp32 encoder output
    float* aW1   = ws + 34078720;
    unsigned short* Wch = (unsigned short*)(ws + 34734080);
    unsigned short* Wcl = (unsigned short*)(ws + 35782656);
    unsigned short* Wfh = (unsigned short*)(ws + 36831232);
    unsigned short* Wfl = (unsigned short*)(ws + 37093376);
    unsigned int* bar   = (unsigned int*)(ws + 37355520);     // 256 uints
    float* S_all = ws + 37355776;         // 2560*512 — deferred only
    unsigned short* a_hi = (unsigned short*)(ws + 38666496);  // 64 MB bf16 plane
    const int deferred = (ws_size >= (size_t)38666496 * sizeof(float)) ? 1 : 0;
    const int bf16ok   = (ws_size >= (size_t)55443712 * sizeof(float)) ? 1 : 0;

    static int attrs_set = 0;
    if (!attrs_set) {
        hipFuncSetAttribute(reinterpret_cast<const void*>(encoder_kernel),
                            hipFuncAttributeMaxDynamicSharedMemorySize, ENC_LDS_BYTES);
        hipFuncSetAttribute(reinterpret_cast<const void*>(gates_kernel),
                            hipFuncAttributeMaxDynamicSharedMemorySize, DEC_LDS_BYTES);
        hipFuncSetAttribute(reinterpret_cast<const void*>(logits_kernel),
                            hipFuncAttributeMaxDynamicSharedMemorySize, DEC_LDS_BYTES);
        attrs_set = 1;
    }

    // zero c_buf + zbuf (contiguous) and encoder flags
    hipMemsetAsync(c_buf, 0, (size_t)262144 * sizeof(float), stream);
    hipMemsetAsync(bar, 0, 256 * sizeof(unsigned int), stream);

    wsplit_cat<<<8192, 256, 0, stream>>>(Wc_ih, Wc_hh, Wch, Wcl);
    wsplit_fc<<<2048, 256, 0, stream>>>(Wfc, Wfh, Wfl);

    {
        unsigned short* ahi_arg = bf16ok ? a_hi : (unsigned short*)nullptr;
        void* args[] = { (void*)&X, (void*)&Wih_f, (void*)&Whh_f, (void*)&b_f,
                         (void*)&Wih_b, (void*)&Whh_b, (void*)&b_b, (void*)&a,
                         (void*)&bar, (void*)&ahi_arg };
        hipLaunchCooperativeKernel(reinterpret_cast<void*>(encoder_kernel),
                                   dim3(256), dim3(512), args, ENC_LDS_BYTES, stream);
    }

    attn_prep<<<1024, 256, 0, stream>>>(a, W1, b1, aW1);

    if (deferred) {
        for (int ty = 0; ty < TYN; ++ty) {
            const float* sprev; int spstr;
            if (ty == 0) { sprev = zbuf; spstr = 512; }
            else { sprev = S_all + (size_t)(ty - 1) * 512; spstr = TYN * 512; }
            float* sout = S_all + (size_t)ty * 512;
            const int sostr = TYN * 512;

            if (bf16ok) {
                attn_bf16_kernel<<<256, 256, 0, stream>>>(aW1, sprev, spstr, W1, W2, b2,
                                                          a_hi, xcat);
            } else {
                attn_kernel<<<256, 256, 0, stream>>>(aW1, sprev, spstr, W1, W2, b2,
                                                     a, xcat);
            }
            gates_kernel<<<256, 256, DEC_LDS_BYTES, stream>>>(
                xcat, sprev, spstr, Wch, Wcl, bc, c_buf, sout, sostr);
        }
        logits_kernel<<<1280, 256, DEC_LDS_BYTES, stream>>>(
            S_all, 512, 80, Wfh, Wfl, bfc, out, VOCAB, 0);
    } else {
        for (int ty = 0; ty < TYN; ++ty) {
            const float* sprev; int spstr;
            float* sout; int sostr;
            if (ty == 0) { sprev = zbuf; spstr = 512; }
            else { sprev = (ty & 1) ? sbufB : zbuf; spstr = 512; }
            sout = (ty & 1) ? zbuf : sbufB; sostr = 512;

            attn_kernel<<<256, 256, 0, stream>>>(aW1, sprev, spstr, W1, W2, b2, a, xcat);
            gates_kernel<<<256, 256, DEC_LDS_BYTES, stream>>>(
                xcat, sprev, spstr, Wch, Wcl, bc, c_buf, sout, sostr);
            logits_kernel<<<128, 256, DEC_LDS_BYTES, stream>>>(
                sout, 512, 8, Wfh, Wfl, bfc, out, TYN * VOCAB, ty * VOCAB);
        }
    }
}